// Round 1
// baseline (1024.609 us; speedup 1.0000x reference)
//
#include <hip/hip_runtime.h>
#include <hip/hip_bf16.h>

// Qwen2 attention layer, MI355X/gfx950.
// B=2 S=2048 HID=3584 NH=28 NKV=4 D=128, causal, GQA groups=7.
// Pipeline: cvt->bf16, fused QKV GEMM (+bias), RoPE(Q,K), V-transpose,
//           flash attention (16-row Q tiles, 32-col KV tiles, MFMA 16x16x32),
//           O-projection GEMM -> f32 out.
// Workspace layout (bytes), total ~99.5 MB:
//   Xb    @ 0          29,360,128  (B*S x HID bf16)      -> reused as AOb after QKV GEMM
//   Wcat  @ 29,360,128 33,030,144  (4608 x 3584 bf16)    -> reused as Wo-bf16 after QKV GEMM
//   bcat  @ 62,390,272 18,432      (4608 f32)
//   QKVb  @ 62,408,704 37,748,736  (B*S x 4608 bf16)
//   Vt    @ 100,157,440 4,194,304  (B*NKV*128 x S bf16)

#define HID   3584
#define NHQ   28
#define NKVH  4
#define HD    128
#define SEQ   2048
#define NQKV  4608
#define GRP   7

typedef __attribute__((ext_vector_type(8))) short bf16x8;
typedef __attribute__((ext_vector_type(4))) float f32x4;

__device__ __forceinline__ void gload_lds16(const void* g, void* l) {
  __builtin_amdgcn_global_load_lds(
      (const __attribute__((address_space(1))) void*)g,
      (__attribute__((address_space(3))) void*)l, 16, 0, 0);
}

__device__ __forceinline__ unsigned short f2bf(float f) {
  __hip_bfloat16 h = __float2bfloat16(f);
  return *reinterpret_cast<unsigned short*>(&h);
}

// ---------------- f32 -> bf16 conversion (vectorized, 4 elems/thread) ------
__global__ __launch_bounds__(256)
void cvt_f32_bf16(const float* __restrict__ src, __hip_bfloat16* __restrict__ dst, int n4) {
  int i = blockIdx.x * 256 + threadIdx.x;
  if (i >= n4) return;
  float4 v = ((const float4*)src)[i];
  ushort4 o;
  o.x = f2bf(v.x); o.y = f2bf(v.y); o.z = f2bf(v.z); o.w = f2bf(v.w);
  ((ushort4*)dst)[i] = o;
}

__global__ __launch_bounds__(256)
void concat_bias(const float* __restrict__ bq, const float* __restrict__ bk,
                 const float* __restrict__ bv, float* __restrict__ out) {
  int i = blockIdx.x * 256 + threadIdx.x;
  if (i < HID) out[i] = bq[i];
  else if (i < HID + 512) out[i] = bk[i - HID];
  else if (i < NQKV) out[i] = bv[i - HID - 512];
}

// ---------------- GEMM: C[M][N] = A[M][K] * B[N][K]^T (+bias) --------------
// 128x128 tile, BK=32, 4 waves (2x2), mfma_f32_16x16x32_bf16 (m97 structure).
template<bool HAS_BIAS, bool OUT_BF16>
__global__ __launch_bounds__(256)
void gemm_bt(const __hip_bfloat16* __restrict__ A, const __hip_bfloat16* __restrict__ Bm,
             const float* __restrict__ bias, void* __restrict__ Cv,
             int M, int N, int K) {
  __shared__ __align__(16) __hip_bfloat16 As[128 * 32];
  __shared__ __align__(16) __hip_bfloat16 Bs[128 * 32];
  const int tid = threadIdx.x;
  const int w = tid >> 6, l = tid & 63;
  const int g = l >> 4, r = l & 15;
  const int wr = w >> 1, wc = w & 1;
  const int bm = blockIdx.x * 128;
  const int bn = blockIdx.y * 128;
  const int lr = l >> 2;        // 0..15: row within a 16-row staging chunk
  const int lc = (l & 3) * 8;   // 0/8/16/24: k-col offset within chunk

  f32x4 acc[4][4];
#pragma unroll
  for (int m = 0; m < 4; m++)
#pragma unroll
    for (int n = 0; n < 4; n++) acc[m][n] = (f32x4){0.f, 0.f, 0.f, 0.f};

  for (int k0 = 0; k0 < K; k0 += 32) {
#pragma unroll
    for (int i = 0; i < 2; i++) {
      const int rb = w * 32 + i * 16;
      gload_lds16(&A[(size_t)(bm + rb + lr) * K + k0 + lc], &As[rb * 32]);
      gload_lds16(&Bm[(size_t)(bn + rb + lr) * K + k0 + lc], &Bs[rb * 32]);
    }
    __syncthreads();
    bf16x8 af[4], bfr[4];
#pragma unroll
    for (int m = 0; m < 4; m++) af[m] = *(const bf16x8*)&As[(wr * 64 + m * 16 + r) * 32 + g * 8];
#pragma unroll
    for (int n = 0; n < 4; n++) bfr[n] = *(const bf16x8*)&Bs[(wc * 64 + n * 16 + r) * 32 + g * 8];
#pragma unroll
    for (int m = 0; m < 4; m++)
#pragma unroll
      for (int n = 0; n < 4; n++)
        acc[m][n] = __builtin_amdgcn_mfma_f32_16x16x32_bf16(af[m], bfr[n], acc[m][n], 0, 0, 0);
    __syncthreads();
  }

#pragma unroll
  for (int m = 0; m < 4; m++) {
#pragma unroll
    for (int n = 0; n < 4; n++) {
      const int gcol = bn + wc * 64 + n * 16 + r;
      const float bv = HAS_BIAS ? bias[gcol] : 0.f;
#pragma unroll
      for (int j = 0; j < 4; j++) {
        const int grow = bm + wr * 64 + m * 16 + 4 * g + j;
        float v = acc[m][n][j] + bv;
        if constexpr (OUT_BF16)
          ((__hip_bfloat16*)Cv)[(size_t)grow * N + gcol] = __float2bfloat16(v);
        else
          ((float*)Cv)[(size_t)grow * N + gcol] = v;
      }
    }
  }
}

// ---------------- RoPE on Q and K head slots (in-place, bf16) --------------
__global__ __launch_bounds__(256)
void rope_qk(__hip_bfloat16* __restrict__ QKV, const float* __restrict__ cosb,
             const float* __restrict__ sinb) {
  int i = blockIdx.x * 256 + threadIdx.x;   // B*S * 32 heads * 64 = 8,388,608
  int d = i & 63;
  int hh = (i >> 6) & 31;
  int row = i >> 11;                         // 0..4095 = b*S+s
  int cb = (hh < NHQ) ? hh * HD : HID + (hh - NHQ) * HD;
  size_t base = (size_t)row * NQKV + cb;
  float c = cosb[row * HD + d];
  float sn = sinb[row * HD + d];
  float x1 = __bfloat162float(QKV[base + d]);
  float x2 = __bfloat162float(QKV[base + d + 64]);
  QKV[base + d] = __float2bfloat16(x1 * c - x2 * sn);
  QKV[base + d + 64] = __float2bfloat16(x2 * c + x1 * sn);
}

// ---------------- V transpose: Vt[b][kv][d][s] = V[b][s][kv][d] ------------
__global__ __launch_bounds__(256)
void v_transpose(const __hip_bfloat16* __restrict__ QKV, __hip_bfloat16* __restrict__ Vt) {
  int i = blockIdx.x * 256 + threadIdx.x;   // 2*4*128*2048 = 2,097,152
  int s = i & (SEQ - 1);
  int d = (i >> 11) & (HD - 1);
  int kv = (i >> 18) & 3;
  int b = i >> 20;
  Vt[i] = QKV[(size_t)(b * SEQ + s) * NQKV + HID + 512 + kv * HD + d];
}

// ---------------- Flash attention: 1 wave, 16-row Q tile, 32-col KV tiles --
__global__ __launch_bounds__(64)
void attn_fwd(const __hip_bfloat16* __restrict__ QKV, const __hip_bfloat16* __restrict__ Vt,
              __hip_bfloat16* __restrict__ AO) {
  const int qt = blockIdx.x;    // 0..127
  const int h = blockIdx.y;     // 0..27
  const int b = blockIdx.z;     // 0..1
  const int kvh = h / GRP;
  const int l = threadIdx.x;
  const int g = l >> 4, r = l & 15;
  const int q0 = qt * 16;
  const float scale = 0.08838834764831845f;  // 1/sqrt(128)

  __shared__ __align__(16) __hip_bfloat16 Plds[16][32];

  const __hip_bfloat16* Qb = QKV + (size_t)(b * SEQ + q0) * NQKV + h * HD;
  const __hip_bfloat16* Kb = QKV + (size_t)(b * SEQ) * NQKV + HID + kvh * HD;
  const __hip_bfloat16* Vb = Vt + (size_t)((b * NKVH + kvh) * HD) * SEQ;

  bf16x8 qf[4];
#pragma unroll
  for (int c = 0; c < 4; c++) qf[c] = *(const bf16x8*)&Qb[(size_t)r * NQKV + c * 32 + g * 8];

  f32x4 of[8];
#pragma unroll
  for (int db = 0; db < 8; db++) of[db] = (f32x4){0.f, 0.f, 0.f, 0.f};
  float mrow[4] = {-1e30f, -1e30f, -1e30f, -1e30f};
  float lsum[4] = {0.f, 0.f, 0.f, 0.f};

  const int ntiles = (q0 + 47) >> 5;
  for (int t = 0; t < ntiles; t++) {
    const int kv0 = t * 32;
    f32x4 s0 = (f32x4){0.f, 0.f, 0.f, 0.f};
    f32x4 s1 = (f32x4){0.f, 0.f, 0.f, 0.f};
#pragma unroll
    for (int c = 0; c < 4; c++) {
      bf16x8 kf = *(const bf16x8*)&Kb[(size_t)(kv0 + r) * NQKV + c * 32 + g * 8];
      s0 = __builtin_amdgcn_mfma_f32_16x16x32_bf16(qf[c], kf, s0, 0, 0, 0);
    }
#pragma unroll
    for (int c = 0; c < 4; c++) {
      bf16x8 kf = *(const bf16x8*)&Kb[(size_t)(kv0 + 16 + r) * NQKV + c * 32 + g * 8];
      s1 = __builtin_amdgcn_mfma_f32_16x16x32_bf16(qf[c], kf, s1, 0, 0, 0);
    }
    float pm[4];
#pragma unroll
    for (int j = 0; j < 4; j++) {
      const int qrow = q0 + 4 * g + j;
      s0[j] = (kv0 + r <= qrow) ? s0[j] * scale : -1e30f;
      s1[j] = (kv0 + 16 + r <= qrow) ? s1[j] * scale : -1e30f;
      pm[j] = fmaxf(s0[j], s1[j]);
    }
#pragma unroll
    for (int mk = 1; mk < 16; mk <<= 1)
#pragma unroll
      for (int j = 0; j < 4; j++) pm[j] = fmaxf(pm[j], __shfl_xor(pm[j], mk, 64));
    float alpha[4], rs[4];
#pragma unroll
    for (int j = 0; j < 4; j++) {
      float nm = fmaxf(mrow[j], pm[j]);
      alpha[j] = __expf(mrow[j] - nm);
      mrow[j] = nm;
      float p0 = __expf(s0[j] - nm);
      float p1 = __expf(s1[j] - nm);
      s0[j] = p0; s1[j] = p1;
      rs[j] = p0 + p1;
    }
#pragma unroll
    for (int mk = 1; mk < 16; mk <<= 1)
#pragma unroll
      for (int j = 0; j < 4; j++) rs[j] += __shfl_xor(rs[j], mk, 64);
#pragma unroll
    for (int j = 0; j < 4; j++) lsum[j] = lsum[j] * alpha[j] + rs[j];
#pragma unroll
    for (int db = 0; db < 8; db++)
#pragma unroll
      for (int j = 0; j < 4; j++) of[db][j] *= alpha[j];

    __syncthreads();
#pragma unroll
    for (int j = 0; j < 4; j++) {
      Plds[4 * g + j][r] = __float2bfloat16(s0[j]);
      Plds[4 * g + j][16 + r] = __float2bfloat16(s1[j]);
    }
    __syncthreads();
    bf16x8 pf = *(const bf16x8*)&Plds[r][g * 8];
#pragma unroll
    for (int db = 0; db < 8; db++) {
      bf16x8 vf = *(const bf16x8*)&Vb[(size_t)(db * 16 + r) * SEQ + kv0 + g * 8];
      of[db] = __builtin_amdgcn_mfma_f32_16x16x32_bf16(pf, vf, of[db], 0, 0, 0);
    }
  }

#pragma unroll
  for (int db = 0; db < 8; db++)
#pragma unroll
    for (int j = 0; j < 4; j++) {
      float o = of[db][j] / lsum[j];
      AO[(size_t)(b * SEQ + q0 + 4 * g + j) * HID + h * HD + db * 16 + r] = __float2bfloat16(o);
    }
}

// ---------------------------------------------------------------------------
extern "C" void kernel_launch(void* const* d_in, const int* in_sizes, int n_in,
                              void* d_out, int out_size, void* d_ws, size_t ws_size,
                              hipStream_t stream) {
  const float* hs = (const float*)d_in[0];
  const float* cosb = (const float*)d_in[1];
  const float* sinb = (const float*)d_in[2];
  const float* Wq = (const float*)d_in[3];
  const float* bq = (const float*)d_in[4];
  const float* Wk = (const float*)d_in[5];
  const float* bk = (const float*)d_in[6];
  const float* Wv = (const float*)d_in[7];
  const float* bv = (const float*)d_in[8];
  const float* Wo = (const float*)d_in[9];

  char* ws = (char*)d_ws;
  __hip_bfloat16* Xb = (__hip_bfloat16*)(ws);
  __hip_bfloat16* Wcat = (__hip_bfloat16*)(ws + 29360128);
  float* bcat = (float*)(ws + 62390272);
  __hip_bfloat16* QKVb = (__hip_bfloat16*)(ws + 62408704);
  __hip_bfloat16* Vt = (__hip_bfloat16*)(ws + 100157440);
  __hip_bfloat16* AOb = Xb;    // X dead after QKV GEMM
  __hip_bfloat16* Wob = Wcat;  // Wcat dead after QKV GEMM

  // Conversions to bf16
  cvt_f32_bf16<<<14336, 256, 0, stream>>>(hs, Xb, 3670016);                       // X
  cvt_f32_bf16<<<12544, 256, 0, stream>>>(Wq, Wcat, 3211264);                     // Wq rows 0..3583
  cvt_f32_bf16<<<1792, 256, 0, stream>>>(Wk, Wcat + (size_t)3584 * 3584, 458752); // Wk rows 3584..4095
  cvt_f32_bf16<<<1792, 256, 0, stream>>>(Wv, Wcat + (size_t)4096 * 3584, 458752); // Wv rows 4096..4607
  concat_bias<<<18, 256, 0, stream>>>(bq, bk, bv, bcat);

  // Fused QKV projection: [4096 x 3584] @ [4608 x 3584]^T + bias -> bf16
  dim3 gq(32, 36);
  gemm_bt<true, true><<<gq, 256, 0, stream>>>(Xb, Wcat, bcat, QKVb, 4096, NQKV, HID);

  // RoPE on Q + K head slots (in place)
  rope_qk<<<32768, 256, 0, stream>>>(QKVb, cosb, sinb);

  // V transpose for PV fragment loads
  v_transpose<<<8192, 256, 0, stream>>>(QKVb, Vt);

  // Wo conversion (into the now-dead Wcat region)
  cvt_f32_bf16<<<12544, 256, 0, stream>>>(Wo, Wob, 3211264);

  // Flash attention
  dim3 ga(128, NHQ, 2);
  attn_fwd<<<ga, 64, 0, stream>>>(QKVb, Vt, AOb);

  // O projection -> f32 out
  dim3 go(32, 28);
  gemm_bt<false, false><<<go, 256, 0, stream>>>(AOb, Wob, nullptr, d_out, 4096, HID, HID);
}

// Round 2
// 704.171 us; speedup vs baseline: 1.4551x; 1.4551x over previous
//
#include <hip/hip_runtime.h>
#include <hip/hip_bf16.h>

// Qwen2 attention layer, MI355X/gfx950.
// B=2 S=2048 HID=3584 NH=28 NKV=4 D=128, causal, GQA groups=7.
// Round 2: attention rewritten as 4-wave blocks, 64-row Q tiles, 64-col KV
// tiles staged in LDS via global_load_lds with pre-swizzled source
// (XOR ((row&7)<<4)) so all MFMA-fragment ds_read_b128 are conflict-free.
//
// Workspace layout (bytes), total ~99.5 MB:
//   Xb    @ 0          29,360,128  (B*S x HID bf16)      -> reused as AOb after QKV GEMM
//   Wcat  @ 29,360,128 33,030,144  (4608 x 3584 bf16)    -> reused as Wo-bf16 after QKV GEMM
//   bcat  @ 62,390,272 18,432      (4608 f32)
//   QKVb  @ 62,408,704 37,748,736  (B*S x 4608 bf16)
//   Vt    @ 100,157,440 4,194,304  (B*NKV*128 x S bf16)

#define HID   3584
#define NHQ   28
#define NKVH  4
#define HD    128
#define SEQ   2048
#define NQKV  4608
#define GRP   7

typedef __attribute__((ext_vector_type(8))) short bf16x8;
typedef __attribute__((ext_vector_type(4))) float f32x4;

__device__ __forceinline__ void gload_lds16(const void* g, void* l) {
  __builtin_amdgcn_global_load_lds(
      (const __attribute__((address_space(1))) void*)g,
      (__attribute__((address_space(3))) void*)l, 16, 0, 0);
}

__device__ __forceinline__ unsigned short f2bf(float f) {
  __hip_bfloat16 h = __float2bfloat16(f);
  return *reinterpret_cast<unsigned short*>(&h);
}

// ---------------- f32 -> bf16 conversion (vectorized, 4 elems/thread) ------
__global__ __launch_bounds__(256)
void cvt_f32_bf16(const float* __restrict__ src, __hip_bfloat16* __restrict__ dst, int n4) {
  int i = blockIdx.x * 256 + threadIdx.x;
  if (i >= n4) return;
  float4 v = ((const float4*)src)[i];
  ushort4 o;
  o.x = f2bf(v.x); o.y = f2bf(v.y); o.z = f2bf(v.z); o.w = f2bf(v.w);
  ((ushort4*)dst)[i] = o;
}

__global__ __launch_bounds__(256)
void concat_bias(const float* __restrict__ bq, const float* __restrict__ bk,
                 const float* __restrict__ bv, float* __restrict__ out) {
  int i = blockIdx.x * 256 + threadIdx.x;
  if (i < HID) out[i] = bq[i];
  else if (i < HID + 512) out[i] = bk[i - HID];
  else if (i < NQKV) out[i] = bv[i - HID - 512];
}

// ---------------- GEMM: C[M][N] = A[M][K] * B[N][K]^T (+bias) --------------
// 128x128 tile, BK=32, 4 waves (2x2), mfma_f32_16x16x32_bf16 (m97 structure).
template<bool HAS_BIAS, bool OUT_BF16>
__global__ __launch_bounds__(256)
void gemm_bt(const __hip_bfloat16* __restrict__ A, const __hip_bfloat16* __restrict__ Bm,
             const float* __restrict__ bias, void* __restrict__ Cv,
             int M, int N, int K) {
  __shared__ __align__(16) __hip_bfloat16 As[128 * 32];
  __shared__ __align__(16) __hip_bfloat16 Bs[128 * 32];
  const int tid = threadIdx.x;
  const int w = tid >> 6, l = tid & 63;
  const int g = l >> 4, r = l & 15;
  const int wr = w >> 1, wc = w & 1;
  const int bm = blockIdx.x * 128;
  const int bn = blockIdx.y * 128;
  const int lr = l >> 2;        // 0..15: row within a 16-row staging chunk
  const int lc = (l & 3) * 8;   // 0/8/16/24: k-col offset within chunk

  f32x4 acc[4][4];
#pragma unroll
  for (int m = 0; m < 4; m++)
#pragma unroll
    for (int n = 0; n < 4; n++) acc[m][n] = (f32x4){0.f, 0.f, 0.f, 0.f};

  for (int k0 = 0; k0 < K; k0 += 32) {
#pragma unroll
    for (int i = 0; i < 2; i++) {
      const int rb = w * 32 + i * 16;
      gload_lds16(&A[(size_t)(bm + rb + lr) * K + k0 + lc], &As[rb * 32]);
      gload_lds16(&Bm[(size_t)(bn + rb + lr) * K + k0 + lc], &Bs[rb * 32]);
    }
    __syncthreads();
    bf16x8 af[4], bfr[4];
#pragma unroll
    for (int m = 0; m < 4; m++) af[m] = *(const bf16x8*)&As[(wr * 64 + m * 16 + r) * 32 + g * 8];
#pragma unroll
    for (int n = 0; n < 4; n++) bfr[n] = *(const bf16x8*)&Bs[(wc * 64 + n * 16 + r) * 32 + g * 8];
#pragma unroll
    for (int m = 0; m < 4; m++)
#pragma unroll
      for (int n = 0; n < 4; n++)
        acc[m][n] = __builtin_amdgcn_mfma_f32_16x16x32_bf16(af[m], bfr[n], acc[m][n], 0, 0, 0);
    __syncthreads();
  }

#pragma unroll
  for (int m = 0; m < 4; m++) {
#pragma unroll
    for (int n = 0; n < 4; n++) {
      const int gcol = bn + wc * 64 + n * 16 + r;
      const float bv = HAS_BIAS ? bias[gcol] : 0.f;
#pragma unroll
      for (int j = 0; j < 4; j++) {
        const int grow = bm + wr * 64 + m * 16 + 4 * g + j;
        float v = acc[m][n][j] + bv;
        if constexpr (OUT_BF16)
          ((__hip_bfloat16*)Cv)[(size_t)grow * N + gcol] = __float2bfloat16(v);
        else
          ((float*)Cv)[(size_t)grow * N + gcol] = v;
      }
    }
  }
}

// ---------------- RoPE on Q and K head slots (in-place, bf16) --------------
__global__ __launch_bounds__(256)
void rope_qk(__hip_bfloat16* __restrict__ QKV, const float* __restrict__ cosb,
             const float* __restrict__ sinb) {
  int i = blockIdx.x * 256 + threadIdx.x;   // B*S * 32 heads * 64 = 8,388,608
  int d = i & 63;
  int hh = (i >> 6) & 31;
  int row = i >> 11;                         // 0..4095 = b*S+s
  int cb = (hh < NHQ) ? hh * HD : HID + (hh - NHQ) * HD;
  size_t base = (size_t)row * NQKV + cb;
  float c = cosb[row * HD + d];
  float sn = sinb[row * HD + d];
  float x1 = __bfloat162float(QKV[base + d]);
  float x2 = __bfloat162float(QKV[base + d + 64]);
  QKV[base + d] = __float2bfloat16(x1 * c - x2 * sn);
  QKV[base + d + 64] = __float2bfloat16(x2 * c + x1 * sn);
}

// ---------------- V transpose: Vt[b][kv][d][s] = V[b][s][kv][d] ------------
__global__ __launch_bounds__(256)
void v_transpose(const __hip_bfloat16* __restrict__ QKV, __hip_bfloat16* __restrict__ Vt) {
  int i = blockIdx.x * 256 + threadIdx.x;   // 2*4*128*2048 = 2,097,152
  int s = i & (SEQ - 1);
  int d = (i >> 11) & (HD - 1);
  int kv = (i >> 18) & 3;
  int b = i >> 20;
  Vt[i] = QKV[(size_t)(b * SEQ + s) * NQKV + HID + 512 + kv * HD + d];
}

// ---------------- Flash attention: 4 waves, 64-row Q tile, 64-col KV tiles -
// K tile [64][128] and V^T tile [128][64] staged in LDS, XOR-swizzled
// (byte ^= (row&7)<<4) via pre-swizzled global source addresses.
__global__ __launch_bounds__(256)
void attn_fwd(const __hip_bfloat16* __restrict__ QKV, const __hip_bfloat16* __restrict__ Vt,
              __hip_bfloat16* __restrict__ AO) {
  const int qt = blockIdx.x;    // 0..31
  const int h = blockIdx.y;     // 0..27
  const int b = blockIdx.z;     // 0..1
  const int kvh = h / GRP;
  const int tid = threadIdx.x;
  const int w = tid >> 6, l = tid & 63;
  const int g = l >> 4, r = l & 15;
  const int q0 = qt * 64;
  const int qw = q0 + w * 16;               // wave's first Q row
  const float scale = 0.08838834764831845f; // 1/sqrt(128)

  __shared__ __align__(16) __hip_bfloat16 Ks[64 * 128];   // 16 KB, swizzled
  __shared__ __align__(16) __hip_bfloat16 Vs[128 * 64];   // 16 KB, swizzled (Vt rows = d)
  __shared__ __align__(16) __hip_bfloat16 Plds[4][16][72]; // 9 KB, per-wave P

  const char* Kb = (const char*)(QKV + (size_t)(b * SEQ) * NQKV + HID + kvh * HD);
  const char* Vb = (const char*)(Vt + (size_t)((b * NKVH + kvh) * HD) * SEQ);
  const __hip_bfloat16* Qb = QKV + (size_t)(b * SEQ + qw) * NQKV + h * HD;

  // Q fragments: wave's 16 rows, K=128 in 4 chunks
  bf16x8 qf[4];
#pragma unroll
  for (int c = 0; c < 4; c++)
    qf[c] = *(const bf16x8*)&Qb[(size_t)r * NQKV + c * 32 + g * 8];

  f32x4 of[8];
#pragma unroll
  for (int db = 0; db < 8; db++) of[db] = (f32x4){0.f, 0.f, 0.f, 0.f};
  float mrow[4] = {-1e30f, -1e30f, -1e30f, -1e30f};
  float lsum[4] = {0.f, 0.f, 0.f, 0.f};

  const int ntiles = qt + 1;
  for (int t = 0; t < ntiles; t++) {
    const int kv0 = t * 64;

    // ---- stage K tile: rows kv0..kv0+63, 256B each. Wave w: rows 16w..16w+15.
#pragma unroll
    for (int p = 0; p < 4; p++) {
      const int row = w * 16 + p * 4 + (l >> 4);     // per-lane row in tile
      const int cb = (l & 15) * 16;                   // byte col within 256B row
      gload_lds16(Kb + (size_t)(kv0 + row) * (NQKV * 2) + (cb ^ ((row & 7) << 4)),
                  (char*)Ks + w * 4096 + p * 1024);
    }
    // ---- stage V^T tile: rows d=0..127, 128B each (cols kv0..kv0+63). Wave w: rows 32w..32w+31.
#pragma unroll
    for (int p = 0; p < 4; p++) {
      const int row = w * 32 + p * 8 + (l >> 3);
      const int cb = (l & 7) * 16;
      gload_lds16(Vb + (size_t)row * (SEQ * 2) + (size_t)kv0 * 2 + (cb ^ ((row & 7) << 4)),
                  (char*)Vs + w * 4096 + p * 1024);
    }
    __syncthreads();

    if (kv0 <= qw + 15) {   // wave has at least one unmasked column in this tile
      // ---- QK^T: 16 rows x 64 cols
      f32x4 s[4];
#pragma unroll
      for (int ks = 0; ks < 4; ks++) s[ks] = (f32x4){0.f, 0.f, 0.f, 0.f};
#pragma unroll
      for (int ks = 0; ks < 4; ks++) {
        const int row = ks * 16 + r;
        const char* kp = (const char*)Ks + row * 256;
#pragma unroll
        for (int c = 0; c < 4; c++) {
          bf16x8 kf = *(const bf16x8*)(kp + ((c * 64 + g * 16) ^ ((row & 7) << 4)));
          s[ks] = __builtin_amdgcn_mfma_f32_16x16x32_bf16(qf[c], kf, s[ks], 0, 0, 0);
        }
      }
      // ---- mask + scale + online softmax
      float pm[4] = {-1e30f, -1e30f, -1e30f, -1e30f};
#pragma unroll
      for (int ks = 0; ks < 4; ks++) {
        const int col = kv0 + ks * 16 + r;
#pragma unroll
        for (int j = 0; j < 4; j++) {
          const int qrow = qw + 4 * g + j;
          s[ks][j] = (col <= qrow) ? s[ks][j] * scale : -1e30f;
          pm[j] = fmaxf(pm[j], s[ks][j]);
        }
      }
#pragma unroll
      for (int mk = 1; mk < 16; mk <<= 1)
#pragma unroll
        for (int j = 0; j < 4; j++) pm[j] = fmaxf(pm[j], __shfl_xor(pm[j], mk, 64));
      float alpha[4], rs[4];
#pragma unroll
      for (int j = 0; j < 4; j++) {
        float nm = fmaxf(mrow[j], pm[j]);
        alpha[j] = __expf(mrow[j] - nm);
        mrow[j] = nm;
        rs[j] = 0.f;
#pragma unroll
        for (int ks = 0; ks < 4; ks++) {
          float p = __expf(s[ks][j] - nm);
          s[ks][j] = p;
          rs[j] += p;
        }
      }
#pragma unroll
      for (int mk = 1; mk < 16; mk <<= 1)
#pragma unroll
        for (int j = 0; j < 4; j++) rs[j] += __shfl_xor(rs[j], mk, 64);
#pragma unroll
      for (int j = 0; j < 4; j++) lsum[j] = lsum[j] * alpha[j] + rs[j];
#pragma unroll
      for (int db = 0; db < 8; db++)
#pragma unroll
        for (int j = 0; j < 4; j++) of[db][j] *= alpha[j];

      // ---- P -> LDS (per-wave, transpose for A-fragment)
#pragma unroll
      for (int ks = 0; ks < 4; ks++)
#pragma unroll
        for (int j = 0; j < 4; j++)
          Plds[w][4 * g + j][ks * 16 + r] = __float2bfloat16(s[ks][j]);

      // ---- PV: P[16][64] x V^T -> of[8] (d = 128)
      bf16x8 pf[2];
#pragma unroll
      for (int c2 = 0; c2 < 2; c2++)
        pf[c2] = *(const bf16x8*)&Plds[w][r][c2 * 32 + g * 8];
#pragma unroll
      for (int db = 0; db < 8; db++) {
#pragma unroll
        for (int c2 = 0; c2 < 2; c2++) {
          const int row = db * 16 + r;
          bf16x8 vf = *(const bf16x8*)((const char*)Vs + row * 128 +
                                       ((c2 * 64 + g * 16) ^ ((row & 7) << 4)));
          of[db] = __builtin_amdgcn_mfma_f32_16x16x32_bf16(pf[c2], vf, of[db], 0, 0, 0);
        }
      }
    }
    __syncthreads();
  }

  // ---- epilogue
#pragma unroll
  for (int db = 0; db < 8; db++)
#pragma unroll
    for (int j = 0; j < 4; j++) {
      float o = of[db][j] / lsum[j];
      AO[(size_t)(b * SEQ + qw + 4 * g + j) * HID + h * HD + db * 16 + r] = __float2bfloat16(o);
    }
}

// ---------------------------------------------------------------------------
extern "C" void kernel_launch(void* const* d_in, const int* in_sizes, int n_in,
                              void* d_out, int out_size, void* d_ws, size_t ws_size,
                              hipStream_t stream) {
  const float* hs = (const float*)d_in[0];
  const float* cosb = (const float*)d_in[1];
  const float* sinb = (const float*)d_in[2];
  const float* Wq = (const float*)d_in[3];
  const float* bq = (const float*)d_in[4];
  const float* Wk = (const float*)d_in[5];
  const float* bk = (const float*)d_in[6];
  const float* Wv = (const float*)d_in[7];
  const float* bv = (const float*)d_in[8];
  const float* Wo = (const float*)d_in[9];

  char* ws = (char*)d_ws;
  __hip_bfloat16* Xb = (__hip_bfloat16*)(ws);
  __hip_bfloat16* Wcat = (__hip_bfloat16*)(ws + 29360128);
  float* bcat = (float*)(ws + 62390272);
  __hip_bfloat16* QKVb = (__hip_bfloat16*)(ws + 62408704);
  __hip_bfloat16* Vt = (__hip_bfloat16*)(ws + 100157440);
  __hip_bfloat16* AOb = Xb;    // X dead after QKV GEMM
  __hip_bfloat16* Wob = Wcat;  // Wcat dead after QKV GEMM

  // Conversions to bf16
  cvt_f32_bf16<<<14336, 256, 0, stream>>>(hs, Xb, 3670016);                       // X
  cvt_f32_bf16<<<12544, 256, 0, stream>>>(Wq, Wcat, 3211264);                     // Wq rows 0..3583
  cvt_f32_bf16<<<1792, 256, 0, stream>>>(Wk, Wcat + (size_t)3584 * 3584, 458752); // Wk rows 3584..4095
  cvt_f32_bf16<<<1792, 256, 0, stream>>>(Wv, Wcat + (size_t)4096 * 3584, 458752); // Wv rows 4096..4607
  concat_bias<<<18, 256, 0, stream>>>(bq, bk, bv, bcat);

  // Fused QKV projection: [4096 x 3584] @ [4608 x 3584]^T + bias -> bf16
  dim3 gq(32, 36);
  gemm_bt<true, true><<<gq, 256, 0, stream>>>(Xb, Wcat, bcat, QKVb, 4096, NQKV, HID);

  // RoPE on Q + K head slots (in place)
  rope_qk<<<32768, 256, 0, stream>>>(QKVb, cosb, sinb);

  // V transpose for PV fragment loads
  v_transpose<<<8192, 256, 0, stream>>>(QKVb, Vt);

  // Wo conversion (into the now-dead Wcat region)
  cvt_f32_bf16<<<12544, 256, 0, stream>>>(Wo, Wob, 3211264);

  // Flash attention: 64-row Q tiles, 4 waves/block
  dim3 ga(32, NHQ, 2);
  attn_fwd<<<ga, 256, 0, stream>>>(QKVb, Vt, AOb);

  // O projection -> f32 out
  dim3 go(32, 28);
  gemm_bt<false, false><<<go, 256, 0, stream>>>(AOb, Wob, nullptr, d_out, 4096, HID, HID);
}